// Round 6
// baseline (3002.368 us; speedup 1.0000x reference)
//
#include <hip/hip_runtime.h>

// ---------------- workspace layout (float offsets) ----------------
static const size_t OFF_WT0  = 0;          // 1536
static const size_t OFF_WT1  = 1536;       // 32768
static const size_t OFF_WT2  = 34304;      // 131072
static const size_t OFF_WT3  = 165376;     // 147456
static const size_t OFF_WR0A = 312832;     // 36864
static const size_t OFF_WR0B = 349696;     // 4096
static const size_t OFF_WR1A = 353792;     // 36864
static const size_t OFF_WR1B = 390656;     // 4096
static const size_t OFF_CB2  = 394752;     // 512
static const size_t OFF_PART = 395264;     // 8192
static const size_t OFF_D2   = 403456;     // 524288
static const size_t OFF_IDX  = 927744;     // 524288 -> ends 1452032
static const size_t BASE     = 1572864;
// common (both paths):
static const size_t OFF_A2   = BASE;              // (64,128,32,32) 8,388,608
static const size_t OFF_A3   = BASE + 8388608;    // 8,388,608
static const size_t OFF_HP   = BASE + 16777216;   // 4 x (64,32,32,32) = 8,388,608
static const size_t OFF_A4   = BASE + 25165824;   // 8,388,608
static const size_t OFF_A5   = BASE + 8388608;    // over dead A3
// half path: A0H @BASE (16.8M), A1h @BASE+16.8M (16.8M)  peak 35.1M fl
static const size_t OFF_A0H  = BASE;
static const size_t OFF_A1H  = BASE + 16777216;
// full path: A0 @BASE (33.5M), A1f @BASE+33.5M (16.7M)   peak 50.3M fl
static const size_t OFF_A0F  = BASE;
static const size_t OFF_A1F  = BASE + 33554432;
static const size_t FULL_NEED_BYTES = (BASE + 50331648) * 4;

// ---------------- weight transpose: w[co][ci][khw] -> wt[ci*KK+khw][co] ----------------
__global__ void wtrans_kernel(const float* __restrict__ w, float* __restrict__ wt,
                              int cin, int cout, int kk) {
  int i = blockIdx.x * 256 + threadIdx.x;
  int total = cin * cout * kk;
  if (i >= total) return;
  int co  = i / (cin * kk);
  int r   = i - co * cin * kk;
  wt[(size_t)r * cout + co] = w[i];
}

// ---------------- codebook squared norms ----------------
__global__ void cb_norm_kernel(const float* __restrict__ cb, float* __restrict__ cb2) {
  int k = blockIdx.x * 256 + threadIdx.x;
  if (k >= 512) return;
  const float4* p = (const float4*)(cb + (size_t)k * 128);
  float s = 0.f;
  for (int j = 0; j < 32; ++j) {
    float4 v = p[j];
    s += v.x * v.x; s += v.y * v.y; s += v.z * v.z; s += v.w * v.w;
  }
  cb2[k] = s;
}

// ---------------- conv: R4 tiling + R5 conflict-free inner loop ----------------
// Wave tile: 256 px x 16 couts (TM=4/lane, TN=16). Per kk:
//   A: 1x ds_read_b128, 64 lanes consecutive (0 conflicts)
//   W: 4x ds_read_b128, wave-uniform address (broadcast)
//   64 v_fmac (128 cyc) -> VALU-bound by construction.
// k is ci-major (ci*K*K+khw) so each chunk = 1-2 channels' halo tile (L2-friendly).
// PARTIAL: k-split over blockIdx.y into KSPLITN partial buffers (no bias/relu).
// IN4: input = relu(sum of 4 partials + bias_in) fused into staging.
template<int CIN,int COUT,int K,int S,int P,int HIN,int WIN,
         int WM,int WN,int KC,int KSPLITN,
         bool RELU_IN,bool RELU_OUT,bool ADD_RES,bool IN4,bool PARTIAL>
__global__ __launch_bounds__(64*WM*WN, 4)
void convq_kernel(const float* __restrict__ in, const float* __restrict__ wt,
                  const float* __restrict__ bias, const float* __restrict__ res,
                  float* __restrict__ out, const float* __restrict__ bias_in)
{
  constexpr int HOUT=(HIN+2*P-K)/S+1;
  constexpr int WOUT=(WIN+2*P-K)/S+1;
  constexpr int THREADS=64*WM*WN;
  constexpr int PM=256*WM;
  constexpr int CO_BLK=16*WN;
  constexpr int KK=K*K;
  constexpr int KTOT=CIN*KK;
  constexpr int KRANGE=KTOT/KSPLITN;
  constexpr size_t HWI=(size_t)HIN*WIN;
  constexpr size_t HWO=(size_t)HOUT*WOUT;
  constexpr size_t IMGSTR=(size_t)64*CIN*HWI;   // partial-buffer stride (IN4)

  __shared__ float A_s[KC*PM];
  __shared__ float W_s[KC*CO_BLK];

  const int tid=threadIdx.x, lane=tid&63, wid=tid>>6;
  const int wm=(WM==1)?0:(wid&(WM-1));
  const int wn=(WM==1)?wid:(wid>>1);
  const int pxw=wm*256+lane*4;
  const int n0=wn*16;

  const int ksl = PARTIAL ? blockIdx.y : 0;
  const int co0 = PARTIAL ? 0 : blockIdx.y*CO_BLK;
  const int base_px = blockIdx.x*PM;
  const int n = blockIdx.z;

  float acc[4][16];
  #pragma unroll
  for (int i=0;i<4;++i)
    #pragma unroll
    for (int j=0;j<16;++j) acc[i][j]=0.f;

  const float* inN = in + (size_t)n*CIN*HWI;

  const int cbeg = ksl*KRANGE, cend = cbeg + KRANGE;
  for (int c0=cbeg; c0<cend; c0+=KC) {
    __syncthreads();
    // stage W[KC][CO_BLK] (coalesced)
    for (int idx=tid; idx<KC*CO_BLK; idx+=THREADS) {
      int kl=idx/CO_BLK, co=idx&(CO_BLK-1);
      W_s[idx]=wt[(size_t)(c0+kl)*COUT+co0+co];
    }
    // stage A[KC][PM] linear (reads stride-1/2, L2-resident halo tile)
    for (int idx=tid; idx<KC*PM; idx+=THREADS) {
      int kl=idx/PM, px=idx&(PM-1);
      int kg=c0+kl;
      int ci=kg/KK, khw=kg%KK;
      int kh=khw/K, kw=khw%K;
      int gpx=base_px+px;
      int oh=gpx/WOUT, ow=gpx%WOUT;
      int ih=oh*S+kh-P, iw=ow*S+kw-P;
      float v=0.f;
      if ((unsigned)ih<(unsigned)HIN && (unsigned)iw<(unsigned)WIN) {
        size_t a=(size_t)ci*HWI+(size_t)ih*WIN+iw;
        if (IN4) {
          v = inN[a]+inN[a+IMGSTR]+inN[a+2*IMGSTR]+inN[a+3*IMGSTR]+bias_in[ci];
          v = fmaxf(v,0.f);
        } else {
          v = inN[a];
          if (RELU_IN) v=fmaxf(v,0.f);
        }
      }
      A_s[kl*PM+px]=v;
    }
    __syncthreads();

    #pragma unroll 4
    for (int kk=0;kk<KC;++kk) {
      float4 a4=*(const float4*)&A_s[kk*PM+pxw];
      float wv[16];
      *(float4*)&wv[0] =*(const float4*)&W_s[kk*CO_BLK+n0];
      *(float4*)&wv[4] =*(const float4*)&W_s[kk*CO_BLK+n0+4];
      *(float4*)&wv[8] =*(const float4*)&W_s[kk*CO_BLK+n0+8];
      *(float4*)&wv[12]=*(const float4*)&W_s[kk*CO_BLK+n0+12];
      float av[4]={a4.x,a4.y,a4.z,a4.w};
      #pragma unroll
      for (int i=0;i<4;++i)
        #pragma unroll
        for (int j=0;j<16;++j)
          acc[i][j]=fmaf(av[i],wv[j],acc[i][j]);
    }
  }

  // epilogue
  float bs[16];
  if (!PARTIAL) {
    #pragma unroll
    for (int j=0;j<16;++j) bs[j]=bias[co0+n0+j];
  }
  const size_t nout = PARTIAL ? (size_t)(ksl*64+n) : (size_t)n;
  #pragma unroll
  for (int j=0;j<16;++j) {
    size_t o=(nout*COUT + co0+n0+j)*HWO + base_px + pxw;
    float4 v;
    v.x=acc[0][j]; v.y=acc[1][j]; v.z=acc[2][j]; v.w=acc[3][j];
    if (!PARTIAL) { v.x+=bs[j]; v.y+=bs[j]; v.z+=bs[j]; v.w+=bs[j]; }
    if (ADD_RES) {
      size_t ro=((size_t)n*COUT + co0+n0+j)*HWO + base_px + pxw;
      float4 r=*(const float4*)&res[ro];
      v.x+=r.x; v.y+=r.y; v.z+=r.z; v.w+=r.w;
    }
    if (RELU_OUT) {
      v.x=fmaxf(v.x,0.f); v.y=fmaxf(v.y,0.f);
      v.z=fmaxf(v.z,0.f); v.w=fmaxf(v.w,0.f);
    }
    *(float4*)&out[o]=v;
  }
}

// ---------------- VQ distance: thread-per-vector, 64-codeword LDS chunks ----------------
__global__ __launch_bounds__(256)
void vq_dist_kernel(const float* __restrict__ enc, const float* __restrict__ cb,
                    const float* __restrict__ cb2, float* __restrict__ d2o,
                    int* __restrict__ io)
{
  __shared__ float cb_s[64 * 128];
  __shared__ float cb2_s[64];
  const int chunk = blockIdx.y;
  const int vec   = blockIdx.x * 256 + threadIdx.x;

  for (int t = threadIdx.x; t < 64 * 128 / 4; t += 256)
    ((float4*)cb_s)[t] = ((const float4*)(cb + (size_t)chunk * 64 * 128))[t];
  if (threadIdx.x < 64) cb2_s[threadIdx.x] = cb2[chunk * 64 + threadIdx.x];
  __syncthreads();

  float4 f[32];
  float f2 = 0.f;
  const float4* fp = (const float4*)(enc + (size_t)vec * 128);
  #pragma unroll
  for (int j = 0; j < 32; ++j) {
    float4 v = fp[j];
    v.x = fmaxf(v.x, 0.f); v.y = fmaxf(v.y, 0.f);
    v.z = fmaxf(v.z, 0.f); v.w = fmaxf(v.w, 0.f);
    f[j] = v;
    f2 += v.x * v.x; f2 += v.y * v.y; f2 += v.z * v.z; f2 += v.w * v.w;
  }

  float best = 3.0e38f;
  int bi = 0;
  for (int k = 0; k < 64; ++k) {
    const float4* ck = (const float4*)(cb_s + k * 128);
    float d0 = 0.f, d1 = 0.f, d2 = 0.f, d3 = 0.f;
    #pragma unroll
    for (int j = 0; j < 32; ++j) {
      float4 c4 = ck[j];
      d0 = fmaf(f[j].x, c4.x, d0);
      d1 = fmaf(f[j].y, c4.y, d1);
      d2 = fmaf(f[j].z, c4.z, d2);
      d3 = fmaf(f[j].w, c4.w, d3);
    }
    float dot = (d0 + d1) + (d2 + d3);
    float dist = fmaf(-2.f, dot, f2) + cb2_s[k];
    if (dist < best) { best = dist; bi = k; }
  }
  d2o[(size_t)chunk * 65536 + vec] = best;
  io [(size_t)chunk * 65536 + vec] = chunk * 64 + bi;
}

// ---------------- gather codeword + commit partials ----------------
__global__ __launch_bounds__(256)
void vq_gather_kernel(const float* __restrict__ enc, const float* __restrict__ cb,
                      const float* __restrict__ d2m, const int* __restrict__ idxs,
                      float* __restrict__ out, float* __restrict__ partial)
{
  const int t   = threadIdx.x;
  const int vec = blockIdx.x * 8 + (t >> 5);
  const int j   = t & 31;

  float best = d2m[vec];
  int bi = idxs[vec];
  #pragma unroll
  for (int c = 1; c < 8; ++c) {
    float d = d2m[(size_t)c * 65536 + vec];
    int  i2 = idxs[(size_t)c * 65536 + vec];
    if (d < best) { best = d; bi = i2; }
  }

  float4 q = ((const float4*)(cb + (size_t)bi * 128))[j];
  float4 f = ((const float4*)(enc + (size_t)vec * 128))[j];
  f.x = fmaxf(f.x, 0.f); f.y = fmaxf(f.y, 0.f);
  f.z = fmaxf(f.z, 0.f); f.w = fmaxf(f.w, 0.f);
  ((float4*)out)[(size_t)vec * 32 + j] = q;

  float dx = q.x - f.x, dy = q.y - f.y, dz = q.z - f.z, dw = q.w - f.w;
  float c = dx * dx + dy * dy + dz * dz + dw * dw;
  #pragma unroll
  for (int off = 32; off > 0; off >>= 1) c += __shfl_down(c, off, 64);
  __shared__ float ls[4];
  if ((t & 63) == 0) ls[t >> 6] = c;
  __syncthreads();
  if (t == 0) partial[blockIdx.x] = (ls[0] + ls[1]) + (ls[2] + ls[3]);
}

__global__ void commit_finalize_kernel(const float* __restrict__ part,
                                       float* __restrict__ outc)
{
  __shared__ double sd[256];
  double s = 0.0;
  for (int i = threadIdx.x; i < 8192; i += 256) s += (double)part[i];
  sd[threadIdx.x] = s;
  __syncthreads();
  for (int off = 128; off > 0; off >>= 1) {
    if (threadIdx.x < off) sd[threadIdx.x] += sd[threadIdx.x + off];
    __syncthreads();
  }
  if (threadIdx.x == 0) *outc = (float)(sd[0] / 8388608.0);
}

// ---------------- launch ----------------
extern "C" void kernel_launch(void* const* d_in, const int* in_sizes, int n_in,
                              void* d_out, int out_size, void* d_ws, size_t ws_size,
                              hipStream_t stream)
{
  (void)in_sizes; (void)n_in; (void)out_size;
  const float* x    = (const float*)d_in[0];
  const float* c0_w = (const float*)d_in[1];
  const float* c0_b = (const float*)d_in[2];
  const float* c1_w = (const float*)d_in[3];
  const float* c1_b = (const float*)d_in[4];
  const float* c2_w = (const float*)d_in[5];
  const float* c2_b = (const float*)d_in[6];
  const float* c3_w = (const float*)d_in[7];
  const float* c3_b = (const float*)d_in[8];
  const float* r0a_w = (const float*)d_in[9];
  const float* r0a_b = (const float*)d_in[10];
  const float* r0b_w = (const float*)d_in[11];
  const float* r0b_b = (const float*)d_in[12];
  const float* r1a_w = (const float*)d_in[13];
  const float* r1a_b = (const float*)d_in[14];
  const float* r1b_w = (const float*)d_in[15];
  const float* r1b_b = (const float*)d_in[16];
  const float* cbk   = (const float*)d_in[17];

  float* out = (float*)d_out;
  float* wsf = (float*)d_ws;

  float* WT0 = wsf + OFF_WT0;
  float* WT1 = wsf + OFF_WT1;
  float* WT2 = wsf + OFF_WT2;
  float* WT3 = wsf + OFF_WT3;
  float* WR0A = wsf + OFF_WR0A;
  float* WR0B = wsf + OFF_WR0B;
  float* WR1A = wsf + OFF_WR1A;
  float* WR1B = wsf + OFF_WR1B;
  float* CB2 = wsf + OFF_CB2;
  float* PT  = wsf + OFF_PART;
  float* D2  = wsf + OFF_D2;
  int*   IX  = (int*)(wsf + OFF_IDX);
  float* A2  = wsf + OFF_A2;
  float* A3  = wsf + OFF_A3;
  float* HP  = wsf + OFF_HP;
  float* A4  = wsf + OFF_A4;
  float* A5  = wsf + OFF_A5;

  // weight prep (ci-major k everywhere)
  wtrans_kernel<<<6,   256, 0, stream>>>(c0_w, WT0, 3, 32, 16);
  wtrans_kernel<<<128, 256, 0, stream>>>(c1_w, WT1, 32, 64, 16);
  wtrans_kernel<<<512, 256, 0, stream>>>(c2_w, WT2, 64, 128, 16);
  wtrans_kernel<<<576, 256, 0, stream>>>(c3_w, WT3, 128, 128, 9);
  wtrans_kernel<<<144, 256, 0, stream>>>(r0a_w, WR0A, 128, 32, 9);
  wtrans_kernel<<<16,  256, 0, stream>>>(r0b_w, WR0B, 32, 128, 1);
  wtrans_kernel<<<144, 256, 0, stream>>>(r1a_w, WR1A, 128, 32, 9);
  wtrans_kernel<<<16,  256, 0, stream>>>(r1b_w, WR1B, 32, 128, 1);
  cb_norm_kernel<<<2, 256, 0, stream>>>(cbk, CB2);

  const float* A1;
  if (ws_size >= FULL_NEED_BYTES) {
    // full batch: bigger grids for conv0/conv1
    float* A0 = wsf + OFF_A0F;
    float* A1f = wsf + OFF_A1F;
    convq_kernel<3,32,4,2,1,256,256, 2,2,16,1, false,true,false,false,false>
        <<<dim3(32,1,64), 256, 0, stream>>>(x, WT0, c0_b, nullptr, A0, nullptr);
    convq_kernel<32,64,4,2,1,128,128, 1,4,32,1, false,true,false,false,false>
        <<<dim3(16,1,64), 256, 0, stream>>>(A0, WT1, c1_b, nullptr, A1f, nullptr);
    A1 = A1f;
  } else {
    // two 32-image halves (ws budget)
    float* A0H = wsf + OFF_A0H;
    float* A1h = wsf + OFF_A1H;
    for (int h = 0; h < 2; ++h) {
      const float* xh = x + (size_t)h * 32 * 3 * 256 * 256;
      convq_kernel<3,32,4,2,1,256,256, 2,2,16,1, false,true,false,false,false>
          <<<dim3(32,1,32), 256, 0, stream>>>(xh, WT0, c0_b, nullptr, A0H, nullptr);
      convq_kernel<32,64,4,2,1,128,128, 1,4,32,1, false,true,false,false,false>
          <<<dim3(16,1,32), 256, 0, stream>>>(A0H, WT1, c1_b, nullptr,
                                              A1h + (size_t)h * 32 * 64 * 64 * 64, nullptr);
    }
    A1 = A1h;
  }

  convq_kernel<64,128,4,2,1,64,64, 1,4,32,1, false,true,false,false,false>
      <<<dim3(4,2,64), 256, 0, stream>>>(A1, WT2, c2_b, nullptr, A2, nullptr);
  convq_kernel<128,128,3,1,1,32,32, 1,4,18,1, false,false,false,false,false>
      <<<dim3(4,2,64), 256, 0, stream>>>(A2, WT3, c3_b, nullptr, A3, nullptr);

  // resblock 0: r0a k-split x4 into HP, r0b fuses sum+bias+relu in staging
  convq_kernel<128,32,3,1,1,32,32, 1,2,18,4, true,false,false,false,true>
      <<<dim3(4,4,64), 128, 0, stream>>>(A3, WR0A, nullptr, nullptr, HP, nullptr);
  convq_kernel<32,128,1,1,0,32,32, 1,4,32,1, false,false,true,true,false>
      <<<dim3(4,2,64), 256, 0, stream>>>(HP, WR0B, r0b_b, A3, A4, r0a_b);
  // resblock 1
  convq_kernel<128,32,3,1,1,32,32, 1,2,18,4, true,false,false,false,true>
      <<<dim3(4,4,64), 128, 0, stream>>>(A4, WR1A, nullptr, nullptr, HP, nullptr);
  convq_kernel<32,128,1,1,0,32,32, 1,4,32,1, false,false,true,true,false>
      <<<dim3(4,2,64), 256, 0, stream>>>(HP, WR1B, r1b_b, A4, A5, r1a_b);

  // VQ (final relu applied on load inside both kernels)
  vq_dist_kernel<<<dim3(256, 8), 256, 0, stream>>>(A5, cbk, CB2, D2, IX);
  vq_gather_kernel<<<8192, 256, 0, stream>>>(A5, cbk, D2, IX, out, PT);
  commit_finalize_kernel<<<1, 256, 0, stream>>>(PT, out + 8388608);
}

// Round 7
// 1511.951 us; speedup vs baseline: 1.9858x; 1.9858x over previous
//
#include <hip/hip_runtime.h>

// ---------------- workspace layout (float offsets) ----------------
static const size_t OFF_WT0  = 0;          // 1536
static const size_t OFF_WT1  = 1536;       // 32768
static const size_t OFF_WT2  = 34304;      // 131072
static const size_t OFF_WT3  = 165376;     // 147456
static const size_t OFF_WR0A = 312832;     // 36864
static const size_t OFF_WR0B = 349696;     // 4096
static const size_t OFF_WR1A = 353792;     // 36864
static const size_t OFF_WR1B = 390656;     // 4096
static const size_t OFF_CB2  = 394752;     // 512
static const size_t OFF_PART = 395264;     // 8192
static const size_t OFF_D2   = 403456;     // 524288
static const size_t OFF_IDX  = 927744;     // 524288 -> ends 1452032
static const size_t BASE     = 1572864;
// half path windows (all within BASE..BASE+33,554,432 -> peak 140.5 MB):
//   conv0/1:  A0H [0,16.8M) + A1h [16.8M,33.6M)
//   conv2:    A2  [0,8.4M)        (A0H dead)
//   conv3:    A3  [8.4M,16.8M)    (atomic-accumulated, zeroed first)
//   r0a/r1a:  HP  [16.8M,25.2M)   (4 partials x 2.1M; A1h dead)
//   r0b:      A4  [25.2M,33.6M)
//   r1b:      A5  [0,8.4M)        (A2 dead)
static const size_t OFF_A0H = BASE;
static const size_t OFF_A1H = BASE + 16777216;
static const size_t OFF_A2  = BASE;
static const size_t OFF_A3  = BASE + 8388608;
static const size_t OFF_HP  = BASE + 16777216;
static const size_t OFF_A4  = BASE + 25165824;
static const size_t OFF_A5  = BASE;
// full-batch path (only if ws allows): A0F [0,33.6M), A1F [33.6M,50.3M)
static const size_t OFF_A0F = BASE;
static const size_t OFF_A1F = BASE + 33554432;
static const size_t FULL_NEED_BYTES = (BASE + 50331648) * 4;

// ---------------- weight transpose: w[co][ci][khw] -> wt[ci*KK+khw][co] ----------------
__global__ void wtrans_kernel(const float* __restrict__ w, float* __restrict__ wt,
                              int cin, int cout, int kk) {
  int i = blockIdx.x * 256 + threadIdx.x;
  int total = cin * cout * kk;
  if (i >= total) return;
  int co = i / (cin * kk);
  int r  = i - co * cin * kk;
  wt[(size_t)r * cout + co] = w[i];
}

// ---------------- codebook squared norms ----------------
__global__ void cb_norm_kernel(const float* __restrict__ cb, float* __restrict__ cb2) {
  int k = blockIdx.x * 256 + threadIdx.x;
  if (k >= 512) return;
  const float4* p = (const float4*)(cb + (size_t)k * 128);
  float s = 0.f;
  for (int j = 0; j < 32; ++j) {
    float4 v = p[j];
    s += v.x * v.x; s += v.y * v.y; s += v.z * v.z; s += v.w * v.w;
  }
  cb2[k] = s;
}

// ---------------- R2 legacy tiled conv + k-split/partial extensions ----------------
// block = 256 threads = 16x16 output tile, thread = 1 pixel, CO accumulators.
// Weights read at wave-uniform addresses -> scalar loads (proven structure).
// INP:    1 = plain input; 4 = input is sum of 4 partial buffers (stride 64*CIN*HW)
// BIN:    add bias_in[ci] to staged input (before RELU_IN)
// KSPLIT: split channel range across blockIdx.y (grid.y = (COUT/CO)*KSPLIT)
// PMODE:  0 = normal epilogue (bias,res,relu); 1 = write partial buffer at
//         image slot (ksl*64+n), raw sums; 2 = atomicAdd raw sums into out
// BRES:   add bias_res[co] to the residual (residual buffer lacks its bias)
template<int CIN,int COUT,int CO,int CC,int K,int S,int P,int HIN,int WIN,
         int INP,int KSPLIT,int PMODE,
         bool BIN,bool RELU_IN,bool RELU_OUT,bool ADD_RES,bool BRES>
__global__ __launch_bounds__(256)
void conv_kernel(const float* __restrict__ in, const float* __restrict__ wt,
                 const float* __restrict__ bias, const float* __restrict__ res,
                 float* __restrict__ out,
                 const float* __restrict__ bias_in,
                 const float* __restrict__ bias_res)
{
  constexpr int HOUT = (HIN + 2 * P - K) / S + 1;
  constexpr int WOUT = (WIN + 2 * P - K) / S + 1;
  constexpr int TW = WOUT / 16;
  constexpr int IT = 15 * S + K;
  constexpr int NCOB = COUT / CO;
  constexpr int CINSPL = CIN / KSPLIT;
  constexpr size_t PST = (size_t)64 * CIN * HIN * WIN;   // partial-buffer stride
  __shared__ float in_s[CC][IT][IT + 1];

  const int tile = blockIdx.x;
  const int by   = blockIdx.y;
  const int ksl  = (KSPLIT == 1) ? 0 : (by / NCOB);
  const int co0  = ((KSPLIT == 1) ? by : (by % NCOB)) * CO;
  const int n    = blockIdx.z;
  const int th   = (tile / TW) * 16;
  const int tw   = (tile % TW) * 16;
  const int tx   = threadIdx.x & 15;
  const int ty   = threadIdx.x >> 4;

  float acc[CO];
  #pragma unroll
  for (int i = 0; i < CO; ++i) acc[i] = 0.f;

  const int ih0 = th * S - P;
  const int iw0 = tw * S - P;
  const float* inN = in + (size_t)n * CIN * HIN * WIN;

  for (int cb0 = ksl * CINSPL; cb0 < (ksl + 1) * CINSPL; cb0 += CC) {
    __syncthreads();
    for (int t = threadIdx.x; t < CC * IT * IT; t += 256) {
      int ci = t / (IT * IT);
      int rm = t - ci * IT * IT;
      int r  = rm / IT;
      int c  = rm - r * IT;
      int ih = ih0 + r, iw = iw0 + c;
      float v = 0.f;
      if (ih >= 0 && ih < HIN && iw >= 0 && iw < WIN) {
        size_t a = (size_t)(cb0 + ci) * HIN * WIN + (size_t)ih * WIN + iw;
        v = inN[a];
        if (INP >= 4) v += inN[a + PST] + inN[a + 2 * PST] + inN[a + 3 * PST];
        if (BIN) v += bias_in[cb0 + ci];
        if (RELU_IN) v = fmaxf(v, 0.f);
      }
      in_s[ci][r][c] = v;
    }
    __syncthreads();
    for (int ci = 0; ci < CC; ++ci) {
      const float* wbase = wt + ((size_t)(cb0 + ci) * K * K) * COUT + co0;
      #pragma unroll
      for (int kh = 0; kh < K; ++kh) {
        #pragma unroll
        for (int kw = 0; kw < K; ++kw) {
          float v = in_s[ci][ty * S + kh][tx * S + kw];
          const float* wrow = wbase + (size_t)(kh * K + kw) * COUT;
          #pragma unroll
          for (int co = 0; co < CO; ++co)
            acc[co] = fmaf(v, wrow[co], acc[co]);
        }
      }
    }
  }

  const int oh = th + ty, ow = tw + tx;
  const size_t HW = (size_t)HOUT * WOUT;
  const size_t pix = (size_t)oh * WOUT + ow;

  if (PMODE == 1) {
    float* outN = out + ((size_t)(ksl * 64 + n) * COUT) * HW;
    #pragma unroll
    for (int co = 0; co < CO; ++co)
      outN[(size_t)(co0 + co) * HW + pix] = acc[co];
  } else if (PMODE == 2) {
    float* outN = out + (size_t)n * COUT * HW;
    #pragma unroll
    for (int co = 0; co < CO; ++co)
      atomicAdd(&outN[(size_t)(co0 + co) * HW + pix], acc[co]);
  } else {
    float* outN = out + (size_t)n * COUT * HW;
    #pragma unroll
    for (int co = 0; co < CO; ++co) {
      float v = acc[co] + bias[co0 + co];
      if (ADD_RES) {
        float r = res[(size_t)n * COUT * HW + (size_t)(co0 + co) * HW + pix];
        if (BRES) r += bias_res[co0 + co];
        v += r;
      }
      if (RELU_OUT) v = fmaxf(v, 0.f);
      outN[(size_t)(co0 + co) * HW + pix] = v;
    }
  }
}

// ---------------- VQ distance: thread-per-vector, 64-codeword LDS chunks ----------------
__global__ __launch_bounds__(256)
void vq_dist_kernel(const float* __restrict__ enc, const float* __restrict__ cb,
                    const float* __restrict__ cb2, float* __restrict__ d2o,
                    int* __restrict__ io)
{
  __shared__ float cb_s[64 * 128];
  __shared__ float cb2_s[64];
  const int chunk = blockIdx.y;
  const int vec   = blockIdx.x * 256 + threadIdx.x;

  for (int t = threadIdx.x; t < 64 * 128 / 4; t += 256)
    ((float4*)cb_s)[t] = ((const float4*)(cb + (size_t)chunk * 64 * 128))[t];
  if (threadIdx.x < 64) cb2_s[threadIdx.x] = cb2[chunk * 64 + threadIdx.x];
  __syncthreads();

  float4 f[32];
  float f2 = 0.f;
  const float4* fp = (const float4*)(enc + (size_t)vec * 128);
  #pragma unroll
  for (int j = 0; j < 32; ++j) {
    float4 v = fp[j];
    v.x = fmaxf(v.x, 0.f); v.y = fmaxf(v.y, 0.f);
    v.z = fmaxf(v.z, 0.f); v.w = fmaxf(v.w, 0.f);
    f[j] = v;
    f2 += v.x * v.x; f2 += v.y * v.y; f2 += v.z * v.z; f2 += v.w * v.w;
  }

  float best = 3.0e38f;
  int bi = 0;
  for (int k = 0; k < 64; ++k) {
    const float4* ck = (const float4*)(cb_s + k * 128);
    float d0 = 0.f, d1 = 0.f, d2 = 0.f, d3 = 0.f;
    #pragma unroll
    for (int j = 0; j < 32; ++j) {
      float4 c4 = ck[j];
      d0 = fmaf(f[j].x, c4.x, d0);
      d1 = fmaf(f[j].y, c4.y, d1);
      d2 = fmaf(f[j].z, c4.z, d2);
      d3 = fmaf(f[j].w, c4.w, d3);
    }
    float dot = (d0 + d1) + (d2 + d3);
    float dist = fmaf(-2.f, dot, f2) + cb2_s[k];
    if (dist < best) { best = dist; bi = k; }
  }
  d2o[(size_t)chunk * 65536 + vec] = best;
  io [(size_t)chunk * 65536 + vec] = chunk * 64 + bi;
}

// ---------------- gather codeword + commit partials ----------------
__global__ __launch_bounds__(256)
void vq_gather_kernel(const float* __restrict__ enc, const float* __restrict__ cb,
                      const float* __restrict__ d2m, const int* __restrict__ idxs,
                      float* __restrict__ out, float* __restrict__ partial)
{
  const int t   = threadIdx.x;
  const int vec = blockIdx.x * 8 + (t >> 5);
  const int j   = t & 31;

  float best = d2m[vec];
  int bi = idxs[vec];
  #pragma unroll
  for (int c = 1; c < 8; ++c) {
    float d = d2m[(size_t)c * 65536 + vec];
    int  i2 = idxs[(size_t)c * 65536 + vec];
    if (d < best) { best = d; bi = i2; }
  }

  float4 q = ((const float4*)(cb + (size_t)bi * 128))[j];
  float4 f = ((const float4*)(enc + (size_t)vec * 128))[j];
  f.x = fmaxf(f.x, 0.f); f.y = fmaxf(f.y, 0.f);
  f.z = fmaxf(f.z, 0.f); f.w = fmaxf(f.w, 0.f);
  ((float4*)out)[(size_t)vec * 32 + j] = q;

  float dx = q.x - f.x, dy = q.y - f.y, dz = q.z - f.z, dw = q.w - f.w;
  float c = dx * dx + dy * dy + dz * dz + dw * dw;
  #pragma unroll
  for (int off = 32; off > 0; off >>= 1) c += __shfl_down(c, off, 64);
  __shared__ float ls[4];
  if ((t & 63) == 0) ls[t >> 6] = c;
  __syncthreads();
  if (t == 0) partial[blockIdx.x] = (ls[0] + ls[1]) + (ls[2] + ls[3]);
}

__global__ void commit_finalize_kernel(const float* __restrict__ part,
                                       float* __restrict__ outc)
{
  __shared__ double sd[256];
  double s = 0.0;
  for (int i = threadIdx.x; i < 8192; i += 256) s += (double)part[i];
  sd[threadIdx.x] = s;
  __syncthreads();
  for (int off = 128; off > 0; off >>= 1) {
    if (threadIdx.x < off) sd[threadIdx.x] += sd[threadIdx.x + off];
    __syncthreads();
  }
  if (threadIdx.x == 0) *outc = (float)(sd[0] / 8388608.0);
}

// ---------------- launch ----------------
extern "C" void kernel_launch(void* const* d_in, const int* in_sizes, int n_in,
                              void* d_out, int out_size, void* d_ws, size_t ws_size,
                              hipStream_t stream)
{
  (void)in_sizes; (void)n_in; (void)out_size;
  const float* x    = (const float*)d_in[0];
  const float* c0_w = (const float*)d_in[1];
  const float* c0_b = (const float*)d_in[2];
  const float* c1_w = (const float*)d_in[3];
  const float* c1_b = (const float*)d_in[4];
  const float* c2_w = (const float*)d_in[5];
  const float* c2_b = (const float*)d_in[6];
  const float* c3_w = (const float*)d_in[7];
  const float* c3_b = (const float*)d_in[8];
  const float* r0a_w = (const float*)d_in[9];
  const float* r0a_b = (const float*)d_in[10];
  const float* r0b_w = (const float*)d_in[11];
  const float* r0b_b = (const float*)d_in[12];
  const float* r1a_w = (const float*)d_in[13];
  const float* r1a_b = (const float*)d_in[14];
  const float* r1b_w = (const float*)d_in[15];
  const float* r1b_b = (const float*)d_in[16];
  const float* cbk   = (const float*)d_in[17];

  float* out = (float*)d_out;
  float* wsf = (float*)d_ws;

  float* WT0 = wsf + OFF_WT0;
  float* WT1 = wsf + OFF_WT1;
  float* WT2 = wsf + OFF_WT2;
  float* WT3 = wsf + OFF_WT3;
  float* WR0A = wsf + OFF_WR0A;
  float* WR0B = wsf + OFF_WR0B;
  float* WR1A = wsf + OFF_WR1A;
  float* WR1B = wsf + OFF_WR1B;
  float* CB2 = wsf + OFF_CB2;
  float* PT  = wsf + OFF_PART;
  float* D2  = wsf + OFF_D2;
  int*   IX  = (int*)(wsf + OFF_IDX);
  float* A2  = wsf + OFF_A2;
  float* A3  = wsf + OFF_A3;
  float* HP  = wsf + OFF_HP;
  float* A4  = wsf + OFF_A4;
  float* A5  = wsf + OFF_A5;

  // weight prep (tiny)
  wtrans_kernel<<<6,   256, 0, stream>>>(c0_w, WT0, 3, 32, 16);
  wtrans_kernel<<<128, 256, 0, stream>>>(c1_w, WT1, 32, 64, 16);
  wtrans_kernel<<<512, 256, 0, stream>>>(c2_w, WT2, 64, 128, 16);
  wtrans_kernel<<<576, 256, 0, stream>>>(c3_w, WT3, 128, 128, 9);
  wtrans_kernel<<<144, 256, 0, stream>>>(r0a_w, WR0A, 128, 32, 9);
  wtrans_kernel<<<16,  256, 0, stream>>>(r0b_w, WR0B, 32, 128, 1);
  wtrans_kernel<<<144, 256, 0, stream>>>(r1a_w, WR1A, 128, 32, 9);
  wtrans_kernel<<<16,  256, 0, stream>>>(r1b_w, WR1B, 32, 128, 1);
  cb_norm_kernel<<<2, 256, 0, stream>>>(cbk, CB2);

  // conv0 + conv1 (R2-exact legacy path)
  const float* A1;
  if (ws_size >= FULL_NEED_BYTES) {
    float* A0 = wsf + OFF_A0F;
    float* A1f = wsf + OFF_A1F;
    conv_kernel<3, 32, 32, 3, 4, 2, 1, 256, 256, 1,1,0, false,false,true,false,false>
        <<<dim3(64, 1, 64), 256, 0, stream>>>(x, WT0, c0_b, nullptr, A0, nullptr, nullptr);
    conv_kernel<32, 64, 64, 8, 4, 2, 1, 128, 128, 1,1,0, false,false,true,false,false>
        <<<dim3(16, 1, 64), 256, 0, stream>>>(A0, WT1, c1_b, nullptr, A1f, nullptr, nullptr);
    A1 = A1f;
  } else {
    float* A0H = wsf + OFF_A0H;
    float* A1h = wsf + OFF_A1H;
    for (int h = 0; h < 2; ++h) {
      const float* xh = x + (size_t)h * 32 * 3 * 256 * 256;
      conv_kernel<3, 32, 32, 3, 4, 2, 1, 256, 256, 1,1,0, false,false,true,false,false>
          <<<dim3(64, 1, 32), 256, 0, stream>>>(xh, WT0, c0_b, nullptr, A0H, nullptr, nullptr);
      conv_kernel<32, 64, 64, 8, 4, 2, 1, 128, 128, 1,1,0, false,false,true,false,false>
          <<<dim3(16, 1, 32), 256, 0, stream>>>(A0H, WT1, c1_b, nullptr,
                                                A1h + (size_t)h * 32 * 64 * 64 * 64,
                                                nullptr, nullptr);
    }
    A1 = A1h;
  }

  // conv2 (R2-exact)
  conv_kernel<64, 128, 64, 8, 4, 2, 1, 64, 64, 1,1,0, false,false,true,false,false>
      <<<dim3(4, 2, 64), 256, 0, stream>>>(A1, WT2, c2_b, nullptr, A2, nullptr, nullptr);

  // conv3: 2-way k-split, atomicAdd into zeroed A3 (raw sums; bias folded into consumers)
  hipMemsetAsync(A3, 0, 8388608 * sizeof(float), stream);
  conv_kernel<128, 128, 64, 8, 3, 1, 1, 32, 32, 1,2,2, false,false,false,false,false>
      <<<dim3(4, 4, 64), 256, 0, stream>>>(A2, WT3, nullptr, nullptr, A3, nullptr, nullptr);

  // resblock 0: r0a 4-way k-split into HP partials; r0b fuses sum+bias+relu in staging
  conv_kernel<128, 32, 16, 8, 3, 1, 1, 32, 32, 1,4,1, true,true,false,false,false>
      <<<dim3(4, 8, 64), 256, 0, stream>>>(A3, WR0A, nullptr, nullptr, HP, c3_b, nullptr);
  conv_kernel<32, 128, 64, 8, 1, 1, 0, 32, 32, 4,1,0, true,true,false,true,true>
      <<<dim3(4, 2, 64), 256, 0, stream>>>(HP, WR0B, r0b_b, A3, A4, r0a_b, c3_b);
  // resblock 1
  conv_kernel<128, 32, 16, 8, 3, 1, 1, 32, 32, 1,4,1, false,true,false,false,false>
      <<<dim3(4, 8, 64), 256, 0, stream>>>(A4, WR1A, nullptr, nullptr, HP, nullptr, nullptr);
  conv_kernel<32, 128, 64, 8, 1, 1, 0, 32, 32, 4,1,0, true,true,false,true,false>
      <<<dim3(4, 2, 64), 256, 0, stream>>>(HP, WR1B, r1b_b, A4, A5, r1a_b, nullptr);

  // VQ (final relu applied on load inside both kernels)
  vq_dist_kernel<<<dim3(256, 8), 256, 0, stream>>>(A5, cbk, CB2, D2, IX);
  vq_gather_kernel<<<8192, 256, 0, stream>>>(A5, cbk, D2, IX, out, PT);
  commit_finalize_kernel<<<1, 256, 0, stream>>>(PT, out + 8388608);
}

// Round 8
// 1349.048 us; speedup vs baseline: 2.2255x; 1.1208x over previous
//
#include <hip/hip_runtime.h>

// ---------------- workspace layout (float offsets) ----------------
static const size_t OFF_WT0  = 0;          // 1536
static const size_t OFF_WT1  = 1536;       // 32768
static const size_t OFF_WT2  = 34304;      // 131072
static const size_t OFF_WT3  = 165376;     // 147456
static const size_t OFF_WR0A = 312832;     // 36864
static const size_t OFF_WR0B = 349696;     // 4096
static const size_t OFF_WR1A = 353792;     // 36864
static const size_t OFF_WR1B = 390656;     // 4096
static const size_t OFF_CB2  = 394752;     // 512
static const size_t OFF_PART = 395264;     // 8192
static const size_t OFF_D2   = 403456;     // 524288
static const size_t OFF_IDX  = 927744;     // 524288 -> ends 1452032
static const size_t BASE     = 1572864;
// half path windows (peak 140.5 MB)
static const size_t OFF_A0H = BASE;
static const size_t OFF_A1H = BASE + 16777216;
static const size_t OFF_A2  = BASE;
static const size_t OFF_A3  = BASE + 8388608;
static const size_t OFF_HP  = BASE + 16777216;
static const size_t OFF_A4  = BASE + 25165824;
static const size_t OFF_A5  = BASE;
// full-batch path (only if ws allows)
static const size_t OFF_A0F = BASE;
static const size_t OFF_A1F = BASE + 33554432;
static const size_t FULL_NEED_BYTES = (BASE + 50331648) * 4;

// ---------------- weight transpose: w[co][ci][khw] -> wt[ci*KK+khw][co] ----------------
__global__ void wtrans_kernel(const float* __restrict__ w, float* __restrict__ wt,
                              int cin, int cout, int kk) {
  int i = blockIdx.x * 256 + threadIdx.x;
  int total = cin * cout * kk;
  if (i >= total) return;
  int co = i / (cin * kk);
  int r  = i - co * cin * kk;
  wt[(size_t)r * cout + co] = w[i];
}

// ---------------- codebook squared norms ----------------
__global__ void cb_norm_kernel(const float* __restrict__ cb, float* __restrict__ cb2) {
  int k = blockIdx.x * 256 + threadIdx.x;
  if (k >= 512) return;
  const float4* p = (const float4*)(cb + (size_t)k * 128);
  float s = 0.f;
  for (int j = 0; j < 32; ++j) {
    float4 v = p[j];
    s += v.x * v.x; s += v.y * v.y; s += v.z * v.z; s += v.w * v.w;
  }
  cb2[k] = s;
}

// ---------------- R2 legacy tiled conv + k-split/partial extensions ----------------
// block = 256 threads = 16x16 output tile, thread = 1 pixel, CO accumulators.
// INP:    1 = plain input; 4 = input is sum of 4 partial buffers (stride 64*CIN*HW)
// BIN:    add bias_in[ci] to staged input (before RELU_IN)
// KSPLIT: split channel range across blockIdx.y (grid.y = (COUT/CO)*KSPLIT)
// PMODE:  0 = normal epilogue; 1 = write partial buffer at image slot ksl*64+n;
//         2 = atomicAdd raw sums into out
// BRES:   add bias_res[co] to the residual
template<int CIN,int COUT,int CO,int CC,int K,int S,int P,int HIN,int WIN,
         int INP,int KSPLIT,int PMODE,
         bool BIN,bool RELU_IN,bool RELU_OUT,bool ADD_RES,bool BRES>
__global__ __launch_bounds__(256)
void conv_kernel(const float* __restrict__ in, const float* __restrict__ wt,
                 const float* __restrict__ bias, const float* __restrict__ res,
                 float* __restrict__ out,
                 const float* __restrict__ bias_in,
                 const float* __restrict__ bias_res)
{
  constexpr int HOUT = (HIN + 2 * P - K) / S + 1;
  constexpr int WOUT = (WIN + 2 * P - K) / S + 1;
  constexpr int TW = WOUT / 16;
  constexpr int IT = 15 * S + K;
  constexpr int NCOB = COUT / CO;
  constexpr int CINSPL = CIN / KSPLIT;
  constexpr size_t PST = (size_t)64 * CIN * HIN * WIN;   // partial-buffer stride
  __shared__ float in_s[CC][IT][IT + 1];

  const int tile = blockIdx.x;
  const int by   = blockIdx.y;
  const int ksl  = (KSPLIT == 1) ? 0 : (by / NCOB);
  const int co0  = ((KSPLIT == 1) ? by : (by % NCOB)) * CO;
  const int n    = blockIdx.z;
  const int th   = (tile / TW) * 16;
  const int tw   = (tile % TW) * 16;
  const int tx   = threadIdx.x & 15;
  const int ty   = threadIdx.x >> 4;

  float acc[CO];
  #pragma unroll
  for (int i = 0; i < CO; ++i) acc[i] = 0.f;

  const int ih0 = th * S - P;
  const int iw0 = tw * S - P;
  const float* inN = in + (size_t)n * CIN * HIN * WIN;

  for (int cb0 = ksl * CINSPL; cb0 < (ksl + 1) * CINSPL; cb0 += CC) {
    __syncthreads();
    for (int t = threadIdx.x; t < CC * IT * IT; t += 256) {
      int ci = t / (IT * IT);
      int rm = t - ci * IT * IT;
      int r  = rm / IT;
      int c  = rm - r * IT;
      int ih = ih0 + r, iw = iw0 + c;
      float v = 0.f;
      if (ih >= 0 && ih < HIN && iw >= 0 && iw < WIN) {
        size_t a = (size_t)(cb0 + ci) * HIN * WIN + (size_t)ih * WIN + iw;
        v = inN[a];
        if (INP >= 4) v += inN[a + PST] + inN[a + 2 * PST] + inN[a + 3 * PST];
        if (BIN) v += bias_in[cb0 + ci];
        if (RELU_IN) v = fmaxf(v, 0.f);
      }
      in_s[ci][r][c] = v;
    }
    __syncthreads();
    for (int ci = 0; ci < CC; ++ci) {
      const float* wbase = wt + ((size_t)(cb0 + ci) * K * K) * COUT + co0;
      #pragma unroll
      for (int kh = 0; kh < K; ++kh) {
        #pragma unroll
        for (int kw = 0; kw < K; ++kw) {
          float v = in_s[ci][ty * S + kh][tx * S + kw];
          const float* wrow = wbase + (size_t)(kh * K + kw) * COUT;
          #pragma unroll
          for (int co = 0; co < CO; ++co)
            acc[co] = fmaf(v, wrow[co], acc[co]);
        }
      }
    }
  }

  const int oh = th + ty, ow = tw + tx;
  const size_t HW = (size_t)HOUT * WOUT;
  const size_t pix = (size_t)oh * WOUT + ow;

  if (PMODE == 1) {
    float* outN = out + ((size_t)(ksl * 64 + n) * COUT) * HW;
    #pragma unroll
    for (int co = 0; co < CO; ++co)
      outN[(size_t)(co0 + co) * HW + pix] = acc[co];
  } else if (PMODE == 2) {
    float* outN = out + (size_t)n * COUT * HW;
    #pragma unroll
    for (int co = 0; co < CO; ++co)
      atomicAdd(&outN[(size_t)(co0 + co) * HW + pix], acc[co]);
  } else {
    float* outN = out + (size_t)n * COUT * HW;
    #pragma unroll
    for (int co = 0; co < CO; ++co) {
      float v = acc[co] + bias[co0 + co];
      if (ADD_RES) {
        float r = res[(size_t)n * COUT * HW + (size_t)(co0 + co) * HW + pix];
        if (BRES) r += bias_res[co0 + co];
        v += r;
      }
      if (RELU_OUT) v = fmaxf(v, 0.f);
      outN[(size_t)(co0 + co) * HW + pix] = v;
    }
  }
}

// ---------------- VQ distance: thread-per-vector, 64-codeword LDS chunks ----------------
__global__ __launch_bounds__(256)
void vq_dist_kernel(const float* __restrict__ enc, const float* __restrict__ cb,
                    const float* __restrict__ cb2, float* __restrict__ d2o,
                    int* __restrict__ io)
{
  __shared__ float cb_s[64 * 128];
  __shared__ float cb2_s[64];
  const int chunk = blockIdx.y;
  const int vec   = blockIdx.x * 256 + threadIdx.x;

  for (int t = threadIdx.x; t < 64 * 128 / 4; t += 256)
    ((float4*)cb_s)[t] = ((const float4*)(cb + (size_t)chunk * 64 * 128))[t];
  if (threadIdx.x < 64) cb2_s[threadIdx.x] = cb2[chunk * 64 + threadIdx.x];
  __syncthreads();

  float4 f[32];
  float f2 = 0.f;
  const float4* fp = (const float4*)(enc + (size_t)vec * 128);
  #pragma unroll
  for (int j = 0; j < 32; ++j) {
    float4 v = fp[j];
    v.x = fmaxf(v.x, 0.f); v.y = fmaxf(v.y, 0.f);
    v.z = fmaxf(v.z, 0.f); v.w = fmaxf(v.w, 0.f);
    f[j] = v;
    f2 += v.x * v.x; f2 += v.y * v.y; f2 += v.z * v.z; f2 += v.w * v.w;
  }

  float best = 3.0e38f;
  int bi = 0;
  for (int k = 0; k < 64; ++k) {
    const float4* ck = (const float4*)(cb_s + k * 128);
    float d0 = 0.f, d1 = 0.f, d2 = 0.f, d3 = 0.f;
    #pragma unroll
    for (int j = 0; j < 32; ++j) {
      float4 c4 = ck[j];
      d0 = fmaf(f[j].x, c4.x, d0);
      d1 = fmaf(f[j].y, c4.y, d1);
      d2 = fmaf(f[j].z, c4.z, d2);
      d3 = fmaf(f[j].w, c4.w, d3);
    }
    float dot = (d0 + d1) + (d2 + d3);
    float dist = fmaf(-2.f, dot, f2) + cb2_s[k];
    if (dist < best) { best = dist; bi = k; }
  }
  d2o[(size_t)chunk * 65536 + vec] = best;
  io [(size_t)chunk * 65536 + vec] = chunk * 64 + bi;
}

// ---------------- gather codeword + commit partials ----------------
__global__ __launch_bounds__(256)
void vq_gather_kernel(const float* __restrict__ enc, const float* __restrict__ cb,
                      const float* __restrict__ d2m, const int* __restrict__ idxs,
                      float* __restrict__ out, float* __restrict__ partial)
{
  const int t   = threadIdx.x;
  const int vec = blockIdx.x * 8 + (t >> 5);
  const int j   = t & 31;

  float best = d2m[vec];
  int bi = idxs[vec];
  #pragma unroll
  for (int c = 1; c < 8; ++c) {
    float d = d2m[(size_t)c * 65536 + vec];
    int  i2 = idxs[(size_t)c * 65536 + vec];
    if (d < best) { best = d; bi = i2; }
  }

  float4 q = ((const float4*)(cb + (size_t)bi * 128))[j];
  float4 f = ((const float4*)(enc + (size_t)vec * 128))[j];
  f.x = fmaxf(f.x, 0.f); f.y = fmaxf(f.y, 0.f);
  f.z = fmaxf(f.z, 0.f); f.w = fmaxf(f.w, 0.f);
  ((float4*)out)[(size_t)vec * 32 + j] = q;

  float dx = q.x - f.x, dy = q.y - f.y, dz = q.z - f.z, dw = q.w - f.w;
  float c = dx * dx + dy * dy + dz * dz + dw * dw;
  #pragma unroll
  for (int off = 32; off > 0; off >>= 1) c += __shfl_down(c, off, 64);
  __shared__ float ls[4];
  if ((t & 63) == 0) ls[t >> 6] = c;
  __syncthreads();
  if (t == 0) partial[blockIdx.x] = (ls[0] + ls[1]) + (ls[2] + ls[3]);
}

__global__ void commit_finalize_kernel(const float* __restrict__ part,
                                       float* __restrict__ outc)
{
  __shared__ double sd[256];
  double s = 0.0;
  for (int i = threadIdx.x; i < 8192; i += 256) s += (double)part[i];
  sd[threadIdx.x] = s;
  __syncthreads();
  for (int off = 128; off > 0; off >>= 1) {
    if (threadIdx.x < off) sd[threadIdx.x] += sd[threadIdx.x + off];
    __syncthreads();
  }
  if (threadIdx.x == 0) *outc = (float)(sd[0] / 8388608.0);
}

// ---------------- launch ----------------
extern "C" void kernel_launch(void* const* d_in, const int* in_sizes, int n_in,
                              void* d_out, int out_size, void* d_ws, size_t ws_size,
                              hipStream_t stream)
{
  (void)in_sizes; (void)n_in; (void)out_size;
  const float* x    = (const float*)d_in[0];
  const float* c0_w = (const float*)d_in[1];
  const float* c0_b = (const float*)d_in[2];
  const float* c1_w = (const float*)d_in[3];
  const float* c1_b = (const float*)d_in[4];
  const float* c2_w = (const float*)d_in[5];
  const float* c2_b = (const float*)d_in[6];
  const float* c3_w = (const float*)d_in[7];
  const float* c3_b = (const float*)d_in[8];
  const float* r0a_w = (const float*)d_in[9];
  const float* r0a_b = (const float*)d_in[10];
  const float* r0b_w = (const float*)d_in[11];
  const float* r0b_b = (const float*)d_in[12];
  const float* r1a_w = (const float*)d_in[13];
  const float* r1a_b = (const float*)d_in[14];
  const float* r1b_w = (const float*)d_in[15];
  const float* r1b_b = (const float*)d_in[16];
  const float* cbk   = (const float*)d_in[17];

  float* out = (float*)d_out;
  float* wsf = (float*)d_ws;

  float* WT0 = wsf + OFF_WT0;
  float* WT1 = wsf + OFF_WT1;
  float* WT2 = wsf + OFF_WT2;
  float* WT3 = wsf + OFF_WT3;
  float* WR0A = wsf + OFF_WR0A;
  float* WR0B = wsf + OFF_WR0B;
  float* WR1A = wsf + OFF_WR1A;
  float* WR1B = wsf + OFF_WR1B;
  float* CB2 = wsf + OFF_CB2;
  float* PT  = wsf + OFF_PART;
  float* D2  = wsf + OFF_D2;
  int*   IX  = (int*)(wsf + OFF_IDX);
  float* A2  = wsf + OFF_A2;
  float* A3  = wsf + OFF_A3;
  float* HP  = wsf + OFF_HP;
  float* A4  = wsf + OFF_A4;
  float* A5  = wsf + OFF_A5;

  // weight prep (tiny)
  wtrans_kernel<<<6,   256, 0, stream>>>(c0_w, WT0, 3, 32, 16);
  wtrans_kernel<<<128, 256, 0, stream>>>(c1_w, WT1, 32, 64, 16);
  wtrans_kernel<<<512, 256, 0, stream>>>(c2_w, WT2, 64, 128, 16);
  wtrans_kernel<<<576, 256, 0, stream>>>(c3_w, WT3, 128, 128, 9);
  wtrans_kernel<<<144, 256, 0, stream>>>(r0a_w, WR0A, 128, 32, 9);
  wtrans_kernel<<<16,  256, 0, stream>>>(r0b_w, WR0B, 32, 128, 1);
  wtrans_kernel<<<144, 256, 0, stream>>>(r1a_w, WR1A, 128, 32, 9);
  wtrans_kernel<<<16,  256, 0, stream>>>(r1b_w, WR1B, 32, 128, 1);
  cb_norm_kernel<<<2, 256, 0, stream>>>(cbk, CB2);

  // conv0 + conv1 (conv1 CO-split x2 -> 1024 blocks)
  const float* A1;
  if (ws_size >= FULL_NEED_BYTES) {
    float* A0 = wsf + OFF_A0F;
    float* A1f = wsf + OFF_A1F;
    conv_kernel<3, 32, 32, 3, 4, 2, 1, 256, 256, 1,1,0, false,false,true,false,false>
        <<<dim3(64, 1, 64), 256, 0, stream>>>(x, WT0, c0_b, nullptr, A0, nullptr, nullptr);
    conv_kernel<32, 64, 32, 8, 4, 2, 1, 128, 128, 1,1,0, false,false,true,false,false>
        <<<dim3(16, 2, 64), 256, 0, stream>>>(A0, WT1, c1_b, nullptr, A1f, nullptr, nullptr);
    A1 = A1f;
  } else {
    float* A0H = wsf + OFF_A0H;
    float* A1h = wsf + OFF_A1H;
    for (int h = 0; h < 2; ++h) {
      const float* xh = x + (size_t)h * 32 * 3 * 256 * 256;
      conv_kernel<3, 32, 32, 3, 4, 2, 1, 256, 256, 1,1,0, false,false,true,false,false>
          <<<dim3(64, 1, 32), 256, 0, stream>>>(xh, WT0, c0_b, nullptr, A0H, nullptr, nullptr);
      conv_kernel<32, 64, 32, 8, 4, 2, 1, 128, 128, 1,1,0, false,false,true,false,false>
          <<<dim3(16, 2, 32), 256, 0, stream>>>(A0H, WT1, c1_b, nullptr,
                                                A1h + (size_t)h * 32 * 64 * 64 * 64,
                                                nullptr, nullptr);
    }
    A1 = A1h;
  }

  // conv2: CO-split x2 -> 1024 blocks
  conv_kernel<64, 128, 32, 8, 4, 2, 1, 64, 64, 1,1,0, false,false,true,false,false>
      <<<dim3(4, 4, 64), 256, 0, stream>>>(A1, WT2, c2_b, nullptr, A2, nullptr, nullptr);

  // conv3: 2-way k-split, atomicAdd into zeroed A3 (bias folded into consumers)
  hipMemsetAsync(A3, 0, 8388608 * sizeof(float), stream);
  conv_kernel<128, 128, 64, 8, 3, 1, 1, 32, 32, 1,2,2, false,false,false,false,false>
      <<<dim3(4, 4, 64), 256, 0, stream>>>(A2, WT3, nullptr, nullptr, A3, nullptr, nullptr);

  // resblock 0: r0a 4-way k-split into HP partials; r0b fuses sum+bias+relu in staging
  conv_kernel<128, 32, 16, 8, 3, 1, 1, 32, 32, 1,4,1, true,true,false,false,false>
      <<<dim3(4, 8, 64), 256, 0, stream>>>(A3, WR0A, nullptr, nullptr, HP, c3_b, nullptr);
  conv_kernel<32, 128, 32, 8, 1, 1, 0, 32, 32, 4,1,0, true,true,false,true,true>
      <<<dim3(4, 4, 64), 256, 0, stream>>>(HP, WR0B, r0b_b, A3, A4, r0a_b, c3_b);
  // resblock 1
  conv_kernel<128, 32, 16, 8, 3, 1, 1, 32, 32, 1,4,1, false,true,false,false,false>
      <<<dim3(4, 8, 64), 256, 0, stream>>>(A4, WR1A, nullptr, nullptr, HP, nullptr, nullptr);
  conv_kernel<32, 128, 32, 8, 1, 1, 0, 32, 32, 4,1,0, true,true,false,true,false>
      <<<dim3(4, 4, 64), 256, 0, stream>>>(HP, WR1B, r1b_b, A4, A5, r1a_b, nullptr);

  // VQ (final relu applied on load inside both kernels)
  vq_dist_kernel<<<dim3(256, 8), 256, 0, stream>>>(A5, cbk, CB2, D2, IX);
  vq_gather_kernel<<<8192, 256, 0, stream>>>(A5, cbk, D2, IX, out, PT);
  commit_finalize_kernel<<<1, 256, 0, stream>>>(PT, out + 8388608);
}

// Round 9
// 1322.904 us; speedup vs baseline: 2.2695x; 1.0198x over previous
//
#include <hip/hip_runtime.h>

// ---------------- workspace layout (float offsets) ----------------
static const size_t OFF_WT0  = 0;          // 1536
static const size_t OFF_WT1  = 1536;       // 32768
static const size_t OFF_WT2  = 34304;      // 131072
static const size_t OFF_WT3  = 165376;     // 147456
static const size_t OFF_WR0A = 312832;     // 36864
static const size_t OFF_WR0B = 349696;     // 4096
static const size_t OFF_WR1A = 353792;     // 36864
static const size_t OFF_WR1B = 390656;     // 4096
static const size_t OFF_CB2  = 394752;     // 512
static const size_t OFF_PART = 395264;     // 8192
static const size_t OFF_D2   = 403456;     // 524288
static const size_t OFF_IDX  = 927744;     // 524288 -> ends 1452032
static const size_t BASE     = 1572864;
// half path windows (peak 140.5 MB)
static const size_t OFF_A0H = BASE;
static const size_t OFF_A1H = BASE + 16777216;
static const size_t OFF_A2  = BASE;
static const size_t OFF_A3  = BASE + 8388608;
static const size_t OFF_HP  = BASE + 16777216;
static const size_t OFF_A4  = BASE + 25165824;
static const size_t OFF_A5  = BASE;
// full-batch path (only if ws allows)
static const size_t OFF_A0F = BASE;
static const size_t OFF_A1F = BASE + 33554432;
static const size_t FULL_NEED_BYTES = (BASE + 50331648) * 4;

// ---------------- weight transpose: w[co][ci][khw] -> wt[ci*KK+khw][co] ----------------
__global__ void wtrans_kernel(const float* __restrict__ w, float* __restrict__ wt,
                              int cin, int cout, int kk) {
  int i = blockIdx.x * 256 + threadIdx.x;
  int total = cin * cout * kk;
  if (i >= total) return;
  int co = i / (cin * kk);
  int r  = i - co * cin * kk;
  wt[(size_t)r * cout + co] = w[i];
}

// ---------------- codebook squared norms ----------------
__global__ void cb_norm_kernel(const float* __restrict__ cb, float* __restrict__ cb2) {
  int k = blockIdx.x * 256 + threadIdx.x;
  if (k >= 512) return;
  const float4* p = (const float4*)(cb + (size_t)k * 128);
  float s = 0.f;
  for (int j = 0; j < 32; ++j) {
    float4 v = p[j];
    s += v.x * v.x; s += v.y * v.y; s += v.z * v.z; s += v.w * v.w;
  }
  cb2[k] = s;
}

// ---------------- R2 legacy tiled conv + k-split/partial extensions ----------------
// block = 256 threads = 16x16 output tile, thread = 1 pixel, CO accumulators.
// INP:    1 = plain input; 4 = input is sum of 4 partial buffers (stride 64*CIN*HW)
// BIN:    add bias_in[ci] to staged input (before RELU_IN)
// KSPLIT: split channel range across blockIdx.y (grid.y = (COUT/CO)*KSPLIT)
// PMODE:  0 = normal epilogue; 1 = write partial buffer at image slot ksl*64+n;
//         2 = atomicAdd raw sums into out
// BRES:   add bias_res[co] to the residual
template<int CIN,int COUT,int CO,int CC,int K,int S,int P,int HIN,int WIN,
         int INP,int KSPLIT,int PMODE,
         bool BIN,bool RELU_IN,bool RELU_OUT,bool ADD_RES,bool BRES>
__global__ __launch_bounds__(256)
void conv_kernel(const float* __restrict__ in, const float* __restrict__ wt,
                 const float* __restrict__ bias, const float* __restrict__ res,
                 float* __restrict__ out,
                 const float* __restrict__ bias_in,
                 const float* __restrict__ bias_res)
{
  constexpr int HOUT = (HIN + 2 * P - K) / S + 1;
  constexpr int WOUT = (WIN + 2 * P - K) / S + 1;
  constexpr int TW = WOUT / 16;
  constexpr int IT = 15 * S + K;
  constexpr int NCOB = COUT / CO;
  constexpr int CINSPL = CIN / KSPLIT;
  constexpr size_t PST = (size_t)64 * CIN * HIN * WIN;   // partial-buffer stride
  __shared__ float in_s[CC][IT][IT + 1];

  const int tile = blockIdx.x;
  const int by   = blockIdx.y;
  const int ksl  = (KSPLIT == 1) ? 0 : (by / NCOB);
  const int co0  = ((KSPLIT == 1) ? by : (by % NCOB)) * CO;
  const int n    = blockIdx.z;
  const int th   = (tile / TW) * 16;
  const int tw   = (tile % TW) * 16;
  const int tx   = threadIdx.x & 15;
  const int ty   = threadIdx.x >> 4;

  float acc[CO];
  #pragma unroll
  for (int i = 0; i < CO; ++i) acc[i] = 0.f;

  const int ih0 = th * S - P;
  const int iw0 = tw * S - P;
  const float* inN = in + (size_t)n * CIN * HIN * WIN;

  for (int cb0 = ksl * CINSPL; cb0 < (ksl + 1) * CINSPL; cb0 += CC) {
    __syncthreads();
    for (int t = threadIdx.x; t < CC * IT * IT; t += 256) {
      int ci = t / (IT * IT);
      int rm = t - ci * IT * IT;
      int r  = rm / IT;
      int c  = rm - r * IT;
      int ih = ih0 + r, iw = iw0 + c;
      float v = 0.f;
      if (ih >= 0 && ih < HIN && iw >= 0 && iw < WIN) {
        size_t a = (size_t)(cb0 + ci) * HIN * WIN + (size_t)ih * WIN + iw;
        v = inN[a];
        if (INP >= 4) v += inN[a + PST] + inN[a + 2 * PST] + inN[a + 3 * PST];
        if (BIN) v += bias_in[cb0 + ci];
        if (RELU_IN) v = fmaxf(v, 0.f);
      }
      in_s[ci][r][c] = v;
    }
    __syncthreads();
    for (int ci = 0; ci < CC; ++ci) {
      const float* wbase = wt + ((size_t)(cb0 + ci) * K * K) * COUT + co0;
      #pragma unroll
      for (int kh = 0; kh < K; ++kh) {
        #pragma unroll
        for (int kw = 0; kw < K; ++kw) {
          float v = in_s[ci][ty * S + kh][tx * S + kw];
          const float* wrow = wbase + (size_t)(kh * K + kw) * COUT;
          #pragma unroll
          for (int co = 0; co < CO; ++co)
            acc[co] = fmaf(v, wrow[co], acc[co]);
        }
      }
    }
  }

  const int oh = th + ty, ow = tw + tx;
  const size_t HW = (size_t)HOUT * WOUT;
  const size_t pix = (size_t)oh * WOUT + ow;

  if (PMODE == 1) {
    float* outN = out + ((size_t)(ksl * 64 + n) * COUT) * HW;
    #pragma unroll
    for (int co = 0; co < CO; ++co)
      outN[(size_t)(co0 + co) * HW + pix] = acc[co];
  } else if (PMODE == 2) {
    float* outN = out + (size_t)n * COUT * HW;
    #pragma unroll
    for (int co = 0; co < CO; ++co)
      atomicAdd(&outN[(size_t)(co0 + co) * HW + pix], acc[co]);
  } else {
    float* outN = out + (size_t)n * COUT * HW;
    #pragma unroll
    for (int co = 0; co < CO; ++co) {
      float v = acc[co] + bias[co0 + co];
      if (ADD_RES) {
        float r = res[(size_t)n * COUT * HW + (size_t)(co0 + co) * HW + pix];
        if (BRES) r += bias_res[co0 + co];
        v += r;
      }
      if (RELU_OUT) v = fmaxf(v, 0.f);
      outN[(size_t)(co0 + co) * HW + pix] = v;
    }
  }
}

// ---------------- VQ distance: thread-per-vector, 64-codeword LDS chunks ----------------
__global__ __launch_bounds__(256)
void vq_dist_kernel(const float* __restrict__ enc, const float* __restrict__ cb,
                    const float* __restrict__ cb2, float* __restrict__ d2o,
                    int* __restrict__ io)
{
  __shared__ float cb_s[64 * 128];
  __shared__ float cb2_s[64];
  const int chunk = blockIdx.y;
  const int vec   = blockIdx.x * 256 + threadIdx.x;

  for (int t = threadIdx.x; t < 64 * 128 / 4; t += 256)
    ((float4*)cb_s)[t] = ((const float4*)(cb + (size_t)chunk * 64 * 128))[t];
  if (threadIdx.x < 64) cb2_s[threadIdx.x] = cb2[chunk * 64 + threadIdx.x];
  __syncthreads();

  float4 f[32];
  float f2 = 0.f;
  const float4* fp = (const float4*)(enc + (size_t)vec * 128);
  #pragma unroll
  for (int j = 0; j < 32; ++j) {
    float4 v = fp[j];
    v.x = fmaxf(v.x, 0.f); v.y = fmaxf(v.y, 0.f);
    v.z = fmaxf(v.z, 0.f); v.w = fmaxf(v.w, 0.f);
    f[j] = v;
    f2 += v.x * v.x; f2 += v.y * v.y; f2 += v.z * v.z; f2 += v.w * v.w;
  }

  float best = 3.0e38f;
  int bi = 0;
  for (int k = 0; k < 64; ++k) {
    const float4* ck = (const float4*)(cb_s + k * 128);
    float d0 = 0.f, d1 = 0.f, d2 = 0.f, d3 = 0.f;
    #pragma unroll
    for (int j = 0; j < 32; ++j) {
      float4 c4 = ck[j];
      d0 = fmaf(f[j].x, c4.x, d0);
      d1 = fmaf(f[j].y, c4.y, d1);
      d2 = fmaf(f[j].z, c4.z, d2);
      d3 = fmaf(f[j].w, c4.w, d3);
    }
    float dot = (d0 + d1) + (d2 + d3);
    float dist = fmaf(-2.f, dot, f2) + cb2_s[k];
    if (dist < best) { best = dist; bi = k; }
  }
  d2o[(size_t)chunk * 65536 + vec] = best;
  io [(size_t)chunk * 65536 + vec] = chunk * 64 + bi;
}

// ---------------- gather codeword + commit partials ----------------
__global__ __launch_bounds__(256)
void vq_gather_kernel(const float* __restrict__ enc, const float* __restrict__ cb,
                      const float* __restrict__ d2m, const int* __restrict__ idxs,
                      float* __restrict__ out, float* __restrict__ partial)
{
  const int t   = threadIdx.x;
  const int vec = blockIdx.x * 8 + (t >> 5);
  const int j   = t & 31;

  float best = d2m[vec];
  int bi = idxs[vec];
  #pragma unroll
  for (int c = 1; c < 8; ++c) {
    float d = d2m[(size_t)c * 65536 + vec];
    int  i2 = idxs[(size_t)c * 65536 + vec];
    if (d < best) { best = d; bi = i2; }
  }

  float4 q = ((const float4*)(cb + (size_t)bi * 128))[j];
  float4 f = ((const float4*)(enc + (size_t)vec * 128))[j];
  f.x = fmaxf(f.x, 0.f); f.y = fmaxf(f.y, 0.f);
  f.z = fmaxf(f.z, 0.f); f.w = fmaxf(f.w, 0.f);
  ((float4*)out)[(size_t)vec * 32 + j] = q;

  float dx = q.x - f.x, dy = q.y - f.y, dz = q.z - f.z, dw = q.w - f.w;
  float c = dx * dx + dy * dy + dz * dz + dw * dw;
  #pragma unroll
  for (int off = 32; off > 0; off >>= 1) c += __shfl_down(c, off, 64);
  __shared__ float ls[4];
  if ((t & 63) == 0) ls[t >> 6] = c;
  __syncthreads();
  if (t == 0) partial[blockIdx.x] = (ls[0] + ls[1]) + (ls[2] + ls[3]);
}

__global__ void commit_finalize_kernel(const float* __restrict__ part,
                                       float* __restrict__ outc)
{
  __shared__ double sd[256];
  double s = 0.0;
  for (int i = threadIdx.x; i < 8192; i += 256) s += (double)part[i];
  sd[threadIdx.x] = s;
  __syncthreads();
  for (int off = 128; off > 0; off >>= 1) {
    if (threadIdx.x < off) sd[threadIdx.x] += sd[threadIdx.x + off];
    __syncthreads();
  }
  if (threadIdx.x == 0) *outc = (float)(sd[0] / 8388608.0);
}

// ---------------- launch ----------------
extern "C" void kernel_launch(void* const* d_in, const int* in_sizes, int n_in,
                              void* d_out, int out_size, void* d_ws, size_t ws_size,
                              hipStream_t stream)
{
  (void)in_sizes; (void)n_in; (void)out_size;
  const float* x    = (const float*)d_in[0];
  const float* c0_w = (const float*)d_in[1];
  const float* c0_b = (const float*)d_in[2];
  const float* c1_w = (const float*)d_in[3];
  const float* c1_b = (const float*)d_in[4];
  const float* c2_w = (const float*)d_in[5];
  const float* c2_b = (const float*)d_in[6];
  const float* c3_w = (const float*)d_in[7];
  const float* c3_b = (const float*)d_in[8];
  const float* r0a_w = (const float*)d_in[9];
  const float* r0a_b = (const float*)d_in[10];
  const float* r0b_w = (const float*)d_in[11];
  const float* r0b_b = (const float*)d_in[12];
  const float* r1a_w = (const float*)d_in[13];
  const float* r1a_b = (const float*)d_in[14];
  const float* r1b_w = (const float*)d_in[15];
  const float* r1b_b = (const float*)d_in[16];
  const float* cbk   = (const float*)d_in[17];

  float* out = (float*)d_out;
  float* wsf = (float*)d_ws;

  float* WT0 = wsf + OFF_WT0;
  float* WT1 = wsf + OFF_WT1;
  float* WT2 = wsf + OFF_WT2;
  float* WT3 = wsf + OFF_WT3;
  float* WR0A = wsf + OFF_WR0A;
  float* WR0B = wsf + OFF_WR0B;
  float* WR1A = wsf + OFF_WR1A;
  float* WR1B = wsf + OFF_WR1B;
  float* CB2 = wsf + OFF_CB2;
  float* PT  = wsf + OFF_PART;
  float* D2  = wsf + OFF_D2;
  int*   IX  = (int*)(wsf + OFF_IDX);
  float* A2  = wsf + OFF_A2;
  float* A3  = wsf + OFF_A3;
  float* HP  = wsf + OFF_HP;
  float* A4  = wsf + OFF_A4;
  float* A5  = wsf + OFF_A5;

  // weight prep (tiny)
  wtrans_kernel<<<6,   256, 0, stream>>>(c0_w, WT0, 3, 32, 16);
  wtrans_kernel<<<128, 256, 0, stream>>>(c1_w, WT1, 32, 64, 16);
  wtrans_kernel<<<512, 256, 0, stream>>>(c2_w, WT2, 64, 128, 16);
  wtrans_kernel<<<576, 256, 0, stream>>>(c3_w, WT3, 128, 128, 9);
  wtrans_kernel<<<144, 256, 0, stream>>>(r0a_w, WR0A, 128, 32, 9);
  wtrans_kernel<<<16,  256, 0, stream>>>(r0b_w, WR0B, 32, 128, 1);
  wtrans_kernel<<<144, 256, 0, stream>>>(r1a_w, WR1A, 128, 32, 9);
  wtrans_kernel<<<16,  256, 0, stream>>>(r1b_w, WR1B, 32, 128, 1);
  cb_norm_kernel<<<2, 256, 0, stream>>>(cbk, CB2);

  // conv0 + conv1 (conv1: CO=32, CC=4 -> 19.2KB LDS -> 8 blocks/CU)
  const float* A1;
  if (ws_size >= FULL_NEED_BYTES) {
    float* A0 = wsf + OFF_A0F;
    float* A1f = wsf + OFF_A1F;
    conv_kernel<3, 32, 32, 3, 4, 2, 1, 256, 256, 1,1,0, false,false,true,false,false>
        <<<dim3(64, 1, 64), 256, 0, stream>>>(x, WT0, c0_b, nullptr, A0, nullptr, nullptr);
    conv_kernel<32, 64, 32, 4, 4, 2, 1, 128, 128, 1,1,0, false,false,true,false,false>
        <<<dim3(16, 2, 64), 256, 0, stream>>>(A0, WT1, c1_b, nullptr, A1f, nullptr, nullptr);
    A1 = A1f;
  } else {
    float* A0H = wsf + OFF_A0H;
    float* A1h = wsf + OFF_A1H;
    for (int h = 0; h < 2; ++h) {
      const float* xh = x + (size_t)h * 32 * 3 * 256 * 256;
      conv_kernel<3, 32, 32, 3, 4, 2, 1, 256, 256, 1,1,0, false,false,true,false,false>
          <<<dim3(64, 1, 32), 256, 0, stream>>>(xh, WT0, c0_b, nullptr, A0H, nullptr, nullptr);
      conv_kernel<32, 64, 32, 4, 4, 2, 1, 128, 128, 1,1,0, false,false,true,false,false>
          <<<dim3(16, 2, 32), 256, 0, stream>>>(A0H, WT1, c1_b, nullptr,
                                                A1h + (size_t)h * 32 * 64 * 64 * 64,
                                                nullptr, nullptr);
    }
    A1 = A1h;
  }

  // conv2: CO=32, CC=4 -> 8 blocks/CU
  conv_kernel<64, 128, 32, 4, 4, 2, 1, 64, 64, 1,1,0, false,false,true,false,false>
      <<<dim3(4, 4, 64), 256, 0, stream>>>(A1, WT2, c2_b, nullptr, A2, nullptr, nullptr);

  // conv3: 2-way k-split + CO=32 -> 2048 blocks, atomicAdd into zeroed A3
  hipMemsetAsync(A3, 0, 8388608 * sizeof(float), stream);
  conv_kernel<128, 128, 32, 8, 3, 1, 1, 32, 32, 1,2,2, false,false,false,false,false>
      <<<dim3(4, 8, 64), 256, 0, stream>>>(A2, WT3, nullptr, nullptr, A3, nullptr, nullptr);

  // resblock 0: r0a 4-way k-split into HP partials; r0b fuses sum+bias+relu in staging
  conv_kernel<128, 32, 16, 8, 3, 1, 1, 32, 32, 1,4,1, true,true,false,false,false>
      <<<dim3(4, 8, 64), 256, 0, stream>>>(A3, WR0A, nullptr, nullptr, HP, c3_b, nullptr);
  conv_kernel<32, 128, 32, 8, 1, 1, 0, 32, 32, 4,1,0, true,true,false,true,true>
      <<<dim3(4, 4, 64), 256, 0, stream>>>(HP, WR0B, r0b_b, A3, A4, r0a_b, c3_b);
  // resblock 1
  conv_kernel<128, 32, 16, 8, 3, 1, 1, 32, 32, 1,4,1, false,true,false,false,false>
      <<<dim3(4, 8, 64), 256, 0, stream>>>(A4, WR1A, nullptr, nullptr, HP, nullptr, nullptr);
  conv_kernel<32, 128, 32, 8, 1, 1, 0, 32, 32, 4,1,0, true,true,false,true,false>
      <<<dim3(4, 4, 64), 256, 0, stream>>>(HP, WR1B, r1b_b, A4, A5, r1a_b, nullptr);

  // VQ (final relu applied on load inside both kernels)
  vq_dist_kernel<<<dim3(256, 8), 256, 0, stream>>>(A5, cbk, CB2, D2, IX);
  vq_gather_kernel<<<8192, 256, 0, stream>>>(A5, cbk, D2, IX, out, PT);
  commit_finalize_kernel<<<1, 256, 0, stream>>>(PT, out + 8388608);
}

// Round 10
// 1315.991 us; speedup vs baseline: 2.2815x; 1.0053x over previous
//
#include <hip/hip_runtime.h>

// ---------------- workspace layout (float offsets) ----------------
static const size_t OFF_WT0  = 0;          // 1536
static const size_t OFF_WT1  = 1536;       // 32768
static const size_t OFF_WT2  = 34304;      // 131072
static const size_t OFF_WT3  = 165376;     // 147456
static const size_t OFF_WR0A = 312832;     // 36864
static const size_t OFF_WR0B = 349696;     // 4096
static const size_t OFF_WR1A = 353792;     // 36864
static const size_t OFF_WR1B = 390656;     // 4096
static const size_t OFF_CB2  = 394752;     // 512
static const size_t OFF_PART = 395264;     // 8192
static const size_t OFF_D2   = 403456;     // 524288
static const size_t OFF_IDX  = 927744;     // 524288 -> ends 1452032
static const size_t BASE     = 1572864;
// half path windows (peak 140.5 MB)
static const size_t OFF_A0H = BASE;
static const size_t OFF_A1H = BASE + 16777216;
static const size_t OFF_A2  = BASE;
static const size_t OFF_A3  = BASE + 8388608;
static const size_t OFF_HP  = BASE + 16777216;
static const size_t OFF_A4  = BASE + 25165824;
static const size_t OFF_A5  = BASE;
// full-batch path (only if ws allows)
static const size_t OFF_A0F = BASE;
static const size_t OFF_A1F = BASE + 33554432;
static const size_t FULL_NEED_BYTES = (BASE + 50331648) * 4;

// ---------------- weight transpose: w[co][ci][khw] -> wt[ci*KK+khw][co] ----------------
__global__ void wtrans_kernel(const float* __restrict__ w, float* __restrict__ wt,
                              int cin, int cout, int kk) {
  int i = blockIdx.x * 256 + threadIdx.x;
  int total = cin * cout * kk;
  if (i >= total) return;
  int co = i / (cin * kk);
  int r  = i - co * cin * kk;
  wt[(size_t)r * cout + co] = w[i];
}

// ---------------- codebook squared norms ----------------
__global__ void cb_norm_kernel(const float* __restrict__ cb, float* __restrict__ cb2) {
  int k = blockIdx.x * 256 + threadIdx.x;
  if (k >= 512) return;
  const float4* p = (const float4*)(cb + (size_t)k * 128);
  float s = 0.f;
  for (int j = 0; j < 32; ++j) {
    float4 v = p[j];
    s += v.x * v.x; s += v.y * v.y; s += v.z * v.z; s += v.w * v.w;
  }
  cb2[k] = s;
}

// ---------------- R2 legacy tiled conv + k-split/partial extensions ----------------
// block = 256 threads = 16x16 output tile, thread = 1 pixel, CO accumulators.
// __launch_bounds__(256, 4): 4 waves/SIMD min -> 128-VGPR budget so acc[CO]
// stays in real VGPRs (default budget forced AGPR spill: accvgpr_read/fmac/
// accvgpr_write = 3x VALU per FMA; VGPR_Count=28 with acc[32] was the tell).
// INP:    1 = plain input; 4 = input is sum of 4 partial buffers (stride 64*CIN*HW)
// BIN:    add bias_in[ci] to staged input (before RELU_IN)
// KSPLIT: split channel range across blockIdx.y (grid.y = (COUT/CO)*KSPLIT)
// PMODE:  0 = normal epilogue; 1 = write partial buffer at image slot ksl*64+n;
//         2 = atomicAdd raw sums into out
// BRES:   add bias_res[co] to the residual
template<int CIN,int COUT,int CO,int CC,int K,int S,int P,int HIN,int WIN,
         int INP,int KSPLIT,int PMODE,
         bool BIN,bool RELU_IN,bool RELU_OUT,bool ADD_RES,bool BRES>
__global__ __launch_bounds__(256, 4)
void conv_kernel(const float* __restrict__ in, const float* __restrict__ wt,
                 const float* __restrict__ bias, const float* __restrict__ res,
                 float* __restrict__ out,
                 const float* __restrict__ bias_in,
                 const float* __restrict__ bias_res)
{
  constexpr int HOUT = (HIN + 2 * P - K) / S + 1;
  constexpr int WOUT = (WIN + 2 * P - K) / S + 1;
  constexpr int TW = WOUT / 16;
  constexpr int IT = 15 * S + K;
  constexpr int NCOB = COUT / CO;
  constexpr int CINSPL = CIN / KSPLIT;
  constexpr size_t PST = (size_t)64 * CIN * HIN * WIN;   // partial-buffer stride
  __shared__ float in_s[CC][IT][IT + 1];

  const int tile = blockIdx.x;
  const int by   = blockIdx.y;
  const int ksl  = (KSPLIT == 1) ? 0 : (by / NCOB);
  const int co0  = ((KSPLIT == 1) ? by : (by % NCOB)) * CO;
  const int n    = blockIdx.z;
  const int th   = (tile / TW) * 16;
  const int tw   = (tile % TW) * 16;
  const int tx   = threadIdx.x & 15;
  const int ty   = threadIdx.x >> 4;

  float acc[CO];
  #pragma unroll
  for (int i = 0; i < CO; ++i) acc[i] = 0.f;

  const int ih0 = th * S - P;
  const int iw0 = tw * S - P;
  const float* inN = in + (size_t)n * CIN * HIN * WIN;

  for (int cb0 = ksl * CINSPL; cb0 < (ksl + 1) * CINSPL; cb0 += CC) {
    __syncthreads();
    for (int t = threadIdx.x; t < CC * IT * IT; t += 256) {
      int ci = t / (IT * IT);
      int rm = t - ci * IT * IT;
      int r  = rm / IT;
      int c  = rm - r * IT;
      int ih = ih0 + r, iw = iw0 + c;
      float v = 0.f;
      if (ih >= 0 && ih < HIN && iw >= 0 && iw < WIN) {
        size_t a = (size_t)(cb0 + ci) * HIN * WIN + (size_t)ih * WIN + iw;
        v = inN[a];
        if (INP >= 4) v += inN[a + PST] + inN[a + 2 * PST] + inN[a + 3 * PST];
        if (BIN) v += bias_in[cb0 + ci];
        if (RELU_IN) v = fmaxf(v, 0.f);
      }
      in_s[ci][r][c] = v;
    }
    __syncthreads();
    for (int ci = 0; ci < CC; ++ci) {
      const float* wbase = wt + ((size_t)(cb0 + ci) * K * K) * COUT + co0;
      #pragma unroll
      for (int kh = 0; kh < K; ++kh) {
        #pragma unroll
        for (int kw = 0; kw < K; ++kw) {
          float v = in_s[ci][ty * S + kh][tx * S + kw];
          const float* wrow = wbase + (size_t)(kh * K + kw) * COUT;
          #pragma unroll
          for (int co = 0; co < CO; ++co)
            acc[co] = fmaf(v, wrow[co], acc[co]);
        }
      }
    }
  }

  const int oh = th + ty, ow = tw + tx;
  const size_t HW = (size_t)HOUT * WOUT;
  const size_t pix = (size_t)oh * WOUT + ow;

  if (PMODE == 1) {
    float* outN = out + ((size_t)(ksl * 64 + n) * COUT) * HW;
    #pragma unroll
    for (int co = 0; co < CO; ++co)
      outN[(size_t)(co0 + co) * HW + pix] = acc[co];
  } else if (PMODE == 2) {
    float* outN = out + (size_t)n * COUT * HW;
    #pragma unroll
    for (int co = 0; co < CO; ++co)
      atomicAdd(&outN[(size_t)(co0 + co) * HW + pix], acc[co]);
  } else {
    float* outN = out + (size_t)n * COUT * HW;
    #pragma unroll
    for (int co = 0; co < CO; ++co) {
      float v = acc[co] + bias[co0 + co];
      if (ADD_RES) {
        float r = res[(size_t)n * COUT * HW + (size_t)(co0 + co) * HW + pix];
        if (BRES) r += bias_res[co0 + co];
        v += r;
      }
      if (RELU_OUT) v = fmaxf(v, 0.f);
      outN[(size_t)(co0 + co) * HW + pix] = v;
    }
  }
}

// ---------------- VQ distance: thread-per-vector, 64-codeword LDS chunks ----------------
// launch_bounds(256,2): 256-VGPR budget so f[32] (128 regs) stays in VGPRs.
__global__ __launch_bounds__(256, 2)
void vq_dist_kernel(const float* __restrict__ enc, const float* __restrict__ cb,
                    const float* __restrict__ cb2, float* __restrict__ d2o,
                    int* __restrict__ io)
{
  __shared__ float cb_s[64 * 128];
  __shared__ float cb2_s[64];
  const int chunk = blockIdx.y;
  const int vec   = blockIdx.x * 256 + threadIdx.x;

  for (int t = threadIdx.x; t < 64 * 128 / 4; t += 256)
    ((float4*)cb_s)[t] = ((const float4*)(cb + (size_t)chunk * 64 * 128))[t];
  if (threadIdx.x < 64) cb2_s[threadIdx.x] = cb2[chunk * 64 + threadIdx.x];
  __syncthreads();

  float4 f[32];
  float f2 = 0.f;
  const float4* fp = (const float4*)(enc + (size_t)vec * 128);
  #pragma unroll
  for (int j = 0; j < 32; ++j) {
    float4 v = fp[j];
    v.x = fmaxf(v.x, 0.f); v.y = fmaxf(v.y, 0.f);
    v.z = fmaxf(v.z, 0.f); v.w = fmaxf(v.w, 0.f);
    f[j] = v;
    f2 += v.x * v.x; f2 += v.y * v.y; f2 += v.z * v.z; f2 += v.w * v.w;
  }

  float best = 3.0e38f;
  int bi = 0;
  for (int k = 0; k < 64; ++k) {
    const float4* ck = (const float4*)(cb_s + k * 128);
    float d0 = 0.f, d1 = 0.f, d2 = 0.f, d3 = 0.f;
    #pragma unroll
    for (int j = 0; j < 32; ++j) {
      float4 c4 = ck[j];
      d0 = fmaf(f[j].x, c4.x, d0);
      d1 = fmaf(f[j].y, c4.y, d1);
      d2 = fmaf(f[j].z, c4.z, d2);
      d3 = fmaf(f[j].w, c4.w, d3);
    }
    float dot = (d0 + d1) + (d2 + d3);
    float dist = fmaf(-2.f, dot, f2) + cb2_s[k];
    if (dist < best) { best = dist; bi = k; }
  }
  d2o[(size_t)chunk * 65536 + vec] = best;
  io [(size_t)chunk * 65536 + vec] = chunk * 64 + bi;
}

// ---------------- gather codeword + commit partials ----------------
__global__ __launch_bounds__(256)
void vq_gather_kernel(const float* __restrict__ enc, const float* __restrict__ cb,
                      const float* __restrict__ d2m, const int* __restrict__ idxs,
                      float* __restrict__ out, float* __restrict__ partial)
{
  const int t   = threadIdx.x;
  const int vec = blockIdx.x * 8 + (t >> 5);
  const int j   = t & 31;

  float best = d2m[vec];
  int bi = idxs[vec];
  #pragma unroll
  for (int c = 1; c < 8; ++c) {
    float d = d2m[(size_t)c * 65536 + vec];
    int  i2 = idxs[(size_t)c * 65536 + vec];
    if (d < best) { best = d; bi = i2; }
  }

  float4 q = ((const float4*)(cb + (size_t)bi * 128))[j];
  float4 f = ((const float4*)(enc + (size_t)vec * 128))[j];
  f.x = fmaxf(f.x, 0.f); f.y = fmaxf(f.y, 0.f);
  f.z = fmaxf(f.z, 0.f); f.w = fmaxf(f.w, 0.f);
  ((float4*)out)[(size_t)vec * 32 + j] = q;

  float dx = q.x - f.x, dy = q.y - f.y, dz = q.z - f.z, dw = q.w - f.w;
  float c = dx * dx + dy * dy + dz * dz + dw * dw;
  #pragma unroll
  for (int off = 32; off > 0; off >>= 1) c += __shfl_down(c, off, 64);
  __shared__ float ls[4];
  if ((t & 63) == 0) ls[t >> 6] = c;
  __syncthreads();
  if (t == 0) partial[blockIdx.x] = (ls[0] + ls[1]) + (ls[2] + ls[3]);
}

__global__ void commit_finalize_kernel(const float* __restrict__ part,
                                       float* __restrict__ outc)
{
  __shared__ double sd[256];
  double s = 0.0;
  for (int i = threadIdx.x; i < 8192; i += 256) s += (double)part[i];
  sd[threadIdx.x] = s;
  __syncthreads();
  for (int off = 128; off > 0; off >>= 1) {
    if (threadIdx.x < off) sd[threadIdx.x] += sd[threadIdx.x + off];
    __syncthreads();
  }
  if (threadIdx.x == 0) *outc = (float)(sd[0] / 8388608.0);
}

// ---------------- launch ----------------
extern "C" void kernel_launch(void* const* d_in, const int* in_sizes, int n_in,
                              void* d_out, int out_size, void* d_ws, size_t ws_size,
                              hipStream_t stream)
{
  (void)in_sizes; (void)n_in; (void)out_size;
  const float* x    = (const float*)d_in[0];
  const float* c0_w = (const float*)d_in[1];
  const float* c0_b = (const float*)d_in[2];
  const float* c1_w = (const float*)d_in[3];
  const float* c1_b = (const float*)d_in[4];
  const float* c2_w = (const float*)d_in[5];
  const float* c2_b = (const float*)d_in[6];
  const float* c3_w = (const float*)d_in[7];
  const float* c3_b = (const float*)d_in[8];
  const float* r0a_w = (const float*)d_in[9];
  const float* r0a_b = (const float*)d_in[10];
  const float* r0b_w = (const float*)d_in[11];
  const float* r0b_b = (const float*)d_in[12];
  const float* r1a_w = (const float*)d_in[13];
  const float* r1a_b = (const float*)d_in[14];
  const float* r1b_w = (const float*)d_in[15];
  const float* r1b_b = (const float*)d_in[16];
  const float* cbk   = (const float*)d_in[17];

  float* out = (float*)d_out;
  float* wsf = (float*)d_ws;

  float* WT0 = wsf + OFF_WT0;
  float* WT1 = wsf + OFF_WT1;
  float* WT2 = wsf + OFF_WT2;
  float* WT3 = wsf + OFF_WT3;
  float* WR0A = wsf + OFF_WR0A;
  float* WR0B = wsf + OFF_WR0B;
  float* WR1A = wsf + OFF_WR1A;
  float* WR1B = wsf + OFF_WR1B;
  float* CB2 = wsf + OFF_CB2;
  float* PT  = wsf + OFF_PART;
  float* D2  = wsf + OFF_D2;
  int*   IX  = (int*)(wsf + OFF_IDX);
  float* A2  = wsf + OFF_A2;
  float* A3  = wsf + OFF_A3;
  float* HP  = wsf + OFF_HP;
  float* A4  = wsf + OFF_A4;
  float* A5  = wsf + OFF_A5;

  // weight prep (tiny)
  wtrans_kernel<<<6,   256, 0, stream>>>(c0_w, WT0, 3, 32, 16);
  wtrans_kernel<<<128, 256, 0, stream>>>(c1_w, WT1, 32, 64, 16);
  wtrans_kernel<<<512, 256, 0, stream>>>(c2_w, WT2, 64, 128, 16);
  wtrans_kernel<<<576, 256, 0, stream>>>(c3_w, WT3, 128, 128, 9);
  wtrans_kernel<<<144, 256, 0, stream>>>(r0a_w, WR0A, 128, 32, 9);
  wtrans_kernel<<<16,  256, 0, stream>>>(r0b_w, WR0B, 32, 128, 1);
  wtrans_kernel<<<144, 256, 0, stream>>>(r1a_w, WR1A, 128, 32, 9);
  wtrans_kernel<<<16,  256, 0, stream>>>(r1b_w, WR1B, 32, 128, 1);
  cb_norm_kernel<<<2, 256, 0, stream>>>(cbk, CB2);

  // conv0 + conv1 (conv1: CO=32, CC=8)
  const float* A1;
  if (ws_size >= FULL_NEED_BYTES) {
    float* A0 = wsf + OFF_A0F;
    float* A1f = wsf + OFF_A1F;
    conv_kernel<3, 32, 32, 3, 4, 2, 1, 256, 256, 1,1,0, false,false,true,false,false>
        <<<dim3(64, 1, 64), 256, 0, stream>>>(x, WT0, c0_b, nullptr, A0, nullptr, nullptr);
    conv_kernel<32, 64, 32, 8, 4, 2, 1, 128, 128, 1,1,0, false,false,true,false,false>
        <<<dim3(16, 2, 64), 256, 0, stream>>>(A0, WT1, c1_b, nullptr, A1f, nullptr, nullptr);
    A1 = A1f;
  } else {
    float* A0H = wsf + OFF_A0H;
    float* A1h = wsf + OFF_A1H;
    for (int h = 0; h < 2; ++h) {
      const float* xh = x + (size_t)h * 32 * 3 * 256 * 256;
      conv_kernel<3, 32, 32, 3, 4, 2, 1, 256, 256, 1,1,0, false,false,true,false,false>
          <<<dim3(64, 1, 32), 256, 0, stream>>>(xh, WT0, c0_b, nullptr, A0H, nullptr, nullptr);
      conv_kernel<32, 64, 32, 8, 4, 2, 1, 128, 128, 1,1,0, false,false,true,false,false>
          <<<dim3(16, 2, 32), 256, 0, stream>>>(A0H, WT1, c1_b, nullptr,
                                                A1h + (size_t)h * 32 * 64 * 64 * 64,
                                                nullptr, nullptr);
    }
    A1 = A1h;
  }

  // conv2: CO=32, CC=8
  conv_kernel<64, 128, 32, 8, 4, 2, 1, 64, 64, 1,1,0, false,false,true,false,false>
      <<<dim3(4, 4, 64), 256, 0, stream>>>(A1, WT2, c2_b, nullptr, A2, nullptr, nullptr);

  // conv3: 2-way k-split + CO=32 -> 2048 blocks, atomicAdd into zeroed A3
  hipMemsetAsync(A3, 0, 8388608 * sizeof(float), stream);
  conv_kernel<128, 128, 32, 8, 3, 1, 1, 32, 32, 1,2,2, false,false,false,false,false>
      <<<dim3(4, 8, 64), 256, 0, stream>>>(A2, WT3, nullptr, nullptr, A3, nullptr, nullptr);

  // resblock 0: r0a 4-way k-split into HP partials; r0b fuses sum+bias+relu in staging
  conv_kernel<128, 32, 16, 8, 3, 1, 1, 32, 32, 1,4,1, true,true,false,false,false>
      <<<dim3(4, 8, 64), 256, 0, stream>>>(A3, WR0A, nullptr, nullptr, HP, c3_b, nullptr);
  conv_kernel<32, 128, 32, 8, 1, 1, 0, 32, 32, 4,1,0, true,true,false,true,true>
      <<<dim3(4, 4, 64), 256, 0, stream>>>(HP, WR0B, r0b_b, A3, A4, r0a_b, c3_b);
  // resblock 1
  conv_kernel<128, 32, 16, 8, 3, 1, 1, 32, 32, 1,4,1, false,true,false,false,false>
      <<<dim3(4, 8, 64), 256, 0, stream>>>(A4, WR1A, nullptr, nullptr, HP, nullptr, nullptr);
  conv_kernel<32, 128, 32, 8, 1, 1, 0, 32, 32, 4,1,0, true,true,false,true,false>
      <<<dim3(4, 4, 64), 256, 0, stream>>>(HP, WR1B, r1b_b, A4, A5, r1a_b, nullptr);

  // VQ (final relu applied on load inside both kernels)
  vq_dist_kernel<<<dim3(256, 8), 256, 0, stream>>>(A5, cbk, CB2, D2, IX);
  vq_gather_kernel<<<8192, 256, 0, stream>>>(A5, cbk, D2, IX, out, PT);
  commit_finalize_kernel<<<1, 256, 0, stream>>>(PT, out + 8388608);
}